// Round 2
// 223.541 us; speedup vs baseline: 1.1193x; 1.1193x over previous
//
#include <hip/hip_runtime.h>

// BERT-CRF fused. Shapes: B=64, S=512, E=1024, T=9.
// d_out: [0]=llh, [1 .. 1+B*S*T)=emission (B,S,T) fp32.
//
// emis_kernel: one wave per 4 rows; per 256-elem chunk load W frag once (36
//   VGPRs) and FMA 4 rows against it (W L1 traffic /4). Butterfly-reduce 9
//   dots, in-register log_softmax. HBM floor ~21 us (134 MB embed).
//
// CRF in LINEAR space: since em is log_softmax, exp(em) rows sum to 1, so
// transfer matrices M_s = exp(trans) o diag(exp(em_s)) have row sums
// ~e^{+-0.1}; products over 511 steps stay within e^{+-15} -> fp32-safe.
//
// crf_fused: one block per batch (64 x 512). The 64 chunk matrices
//   (20.7 KB/batch) never leave LDS -> d_ws completely unused, one fewer
//   launch, no global round-trip. Phase A: each wave computes 7 chunks in
//   parallel (lane = 9*g + i, 63/64 lanes active); R starts as identity row
//   so every E[] access is compile-time-indexed (no dynamic VGPR indexing ->
//   no scratch). Phase B: append-buffer LDS tree (depth 6, no in-place
//   race). Phase C: numerator (1 step/thread at 512 threads) + llh.

#define BB 64
#define SS 512
#define EE 1024
#define TT 9

__global__ __launch_bounds__(256) void emis_kernel(
    const float* __restrict__ embed,   // (B*S, E)
    const float* __restrict__ W,       // (T, E)
    const float* __restrict__ bias,    // (T)
    float* __restrict__ out)           // [0]=llh, [1..]=emission
{
    if (blockIdx.x == 0 && threadIdx.x == 0) out[0] = 0.0f;  // llh accumulator

    const int wid  = threadIdx.x >> 6;
    const int lane = threadIdx.x & 63;
    const int row0 = blockIdx.x * 16 + wid * 4;  // 4 rows per wave

    float acc[4][TT];
#pragma unroll
    for (int r = 0; r < 4; ++r)
#pragma unroll
        for (int t = 0; t < TT; ++t) acc[r][t] = 0.0f;

    // E=1024 = 4 chunks x (64 lanes x 4 floats); W frag reused across 4 rows
#pragma unroll
    for (int k = 0; k < 4; ++k) {
        const int off = k * 256 + 4 * lane;
        float4 w[TT];
#pragma unroll
        for (int t = 0; t < TT; ++t)
            w[t] = *(const float4*)(W + t * EE + off);
#pragma unroll
        for (int r = 0; r < 4; ++r) {
            const float4 x = *(const float4*)(embed + (size_t)(row0 + r) * EE + off);
#pragma unroll
            for (int t = 0; t < TT; ++t)
                acc[r][t] += x.x * w[t].x + x.y * w[t].y + x.z * w[t].z + x.w * w[t].w;
        }
    }

#pragma unroll
    for (int r = 0; r < 4; ++r) {
#pragma unroll
        for (int t = 0; t < TT; ++t) {
#pragma unroll
            for (int o = 32; o > 0; o >>= 1)
                acc[r][t] += __shfl_xor(acc[r][t], o, 64);
            acc[r][t] += bias[t];
        }
        float m = acc[r][0];
#pragma unroll
        for (int t = 1; t < TT; ++t) m = fmaxf(m, acc[r][t]);
        float ssum = 0.0f;
#pragma unroll
        for (int t = 0; t < TT; ++t) ssum += __expf(acc[r][t] - m);
        const float lse = m + __logf(ssum);

        float val = acc[r][0];
#pragma unroll
        for (int t = 1; t < TT; ++t) val = (lane == t) ? acc[r][t] : val;
        if (lane < TT)
            out[1 + (size_t)(row0 + r) * TT + lane] = val - lse;
    }
}

// ---- fused CRF: chunk products in LDS + tree reduction + numerator ----
__global__ __launch_bounds__(512) void crf_fused(
    const float* __restrict__ outbase,  // d_out ([0]=llh, em at +1)
    const int* __restrict__ tags,
    const int* __restrict__ mask,
    const float* __restrict__ start_t,
    const float* __restrict__ end_t,
    const float* __restrict__ trans,
    float* __restrict__ out)
{
    __shared__ float mats[127 * 81];   // 64 chunk mats + 32+16+8+4+2+1 levels
    __shared__ float red[8];
    __shared__ float redm[8];

    const int b    = blockIdx.x;
    const int tid  = threadIdx.x;
    const int lane = tid & 63;
    const int wid  = tid >> 6;         // 8 waves
    const float* em = outbase + 1 + (size_t)b * SS * TT;

    // E = exp(trans): lane-uniform, 81 VGPRs (only ever indexed with
    // compile-time constants -> stays in registers)
    float E[TT * TT];
#pragma unroll
    for (int e = 0; e < TT * TT; ++e) E[e] = __expf(trans[e]);

    // ---- Phase A: 64 chunk products -> mats[c*81 + i*9 + j] ----
    // 7 chunks per wave-pass: lane = 9*g + i  (g = chunk-in-group, i = row)
    const int g = lane / TT;
    const int i = lane - g * TT;
    const bool lact = (lane < 63);

    for (int grp = wid; grp < 10; grp += 8) {   // 10 groups of 7 chunks
        const int c = grp * 7 + g;
        const bool cact = lact && (c < 64);
        const int cc = cact ? c : 0;            // clamp addresses for idle lanes
        const int s0 = 8 * cc + 1;              // first step of chunk

        // R = row i of running product; start as identity row so the first
        // masked-in step computes E[i][:]*p[:] via the generic FMA path
        // (all E indices compile-time -> no dynamic VGPR indexing).
        float R[TT];
#pragma unroll
        for (int k = 0; k < TT; ++k) R[k] = (k == i) ? 1.0f : 0.0f;

#pragma unroll
        for (int d = 0; d < 8; ++d) {
            const int s = s0 + d;
            const bool valid = (s < SS);        // chunk 63 has only 7 steps
            const int sc = valid ? s : (SS - 1);
            float p[TT];
#pragma unroll
            for (int j = 0; j < TT; ++j) p[j] = __expf(em[sc * TT + j]);
            const int mk = (cact && valid) ? mask[b * SS + sc] : 0;

            float nR[TT];
#pragma unroll
            for (int j = 0; j < TT; ++j) {
                float a = 0.0f;
#pragma unroll
                for (int k = 0; k < TT; ++k) a += R[k] * E[k * TT + j];
                nR[j] = a * p[j];
            }
#pragma unroll
            for (int j = 0; j < TT; ++j) R[j] = mk ? nR[j] : R[j];
        }
        if (cact) {
#pragma unroll
            for (int j = 0; j < TT; ++j)
                mats[c * 81 + i * TT + j] = R[j];
        }
    }

    // ---- numerator: exactly one step per thread (SS == 512 == blockDim) ----
    float num = 0.0f;
    int msum = 0;
    {
        const int s = tid;
        const int mk = mask[b * SS + s];
        msum = mk;
        const int tg = tags[b * SS + s];
        if (s == 0) {
            num = start_t[tg] + em[tg];
        } else {
            const int tp = tags[b * SS + s - 1];
            num = (float)mk * (trans[tp * TT + tg] + em[s * TT + tg]);
        }
    }
#pragma unroll
    for (int o = 32; o > 0; o >>= 1) {
        num += __shfl_xor(num, o, 64);
        msum += __shfl_xor(msum, o, 64);
    }
    if (lane == 0) { red[wid] = num; redm[wid] = (float)msum; }
    __syncthreads();   // phase-A writes + red[] now visible

    // ---- tree reduction: levels n = 32,16,8,4,2,1, append-buffer ----
    int inOff = 0, outOff = 64;
    for (int n = 32; n >= 1; n >>= 1) {
        for (int c = wid; c < n; c += 8) {
            const float* A  = mats + (inOff + 2 * c) * 81;
            const float* Bm = mats + (inOff + 2 * c + 1) * 81;
            float* C = mats + (outOff + c) * 81;
            int e = lane;                       // entries 0..63
            int ii = e / 9, jj = e - ii * 9;
            float a = 0.0f;
#pragma unroll
            for (int k = 0; k < TT; ++k) a += A[ii * 9 + k] * Bm[k * 9 + jj];
            C[e] = a;
            if (lane < 17) {                    // entries 64..80
                e = 64 + lane; ii = e / 9; jj = e - ii * 9;
                float a2 = 0.0f;
#pragma unroll
                for (int k = 0; k < TT; ++k) a2 += A[ii * 9 + k] * Bm[k * 9 + jj];
                C[e] = a2;
            }
        }
        __syncthreads();
        inOff = outOff; outOff += n;
    }
    // Mtot at mats + 126*81

    if (wid == 0) {
        const float* Mt = mats + 126 * 81;
        float v0[TT];
#pragma unroll
        for (int i2 = 0; i2 < TT; ++i2) v0[i2] = __expf(start_t[i2] + em[i2]);
        const int j = (lane < TT) ? lane : 0;
        float cs = 0.0f;
#pragma unroll
        for (int i2 = 0; i2 < TT; ++i2) cs += v0[i2] * Mt[i2 * 9 + j];
        float val = cs * __expf(end_t[j]);
        if (lane >= TT) val = 0.0f;
#pragma unroll
        for (int o = 8; o > 0; o >>= 1) val += __shfl_xor(val, o, 64);
        if (lane == 0) {
            const float den = __logf(val);
            float numT = red[0] + red[1] + red[2] + red[3]
                       + red[4] + red[5] + red[6] + red[7];
            const int ms = (int)(redm[0] + redm[1] + redm[2] + redm[3]
                               + redm[4] + redm[5] + redm[6] + redm[7]);
            numT += end_t[tags[b * SS + (ms - 1)]];
            atomicAdd(out, numT - den);
        }
    }
}

extern "C" void kernel_launch(void* const* d_in, const int* in_sizes, int n_in,
                              void* d_out, int out_size, void* d_ws, size_t ws_size,
                              hipStream_t stream) {
    const float* embed   = (const float*)d_in[0];
    const int*   tags    = (const int*)d_in[1];
    const int*   mask    = (const int*)d_in[2];
    const float* W       = (const float*)d_in[3];
    const float* bias    = (const float*)d_in[4];
    const float* start_t = (const float*)d_in[5];
    const float* end_t   = (const float*)d_in[6];
    const float* trans   = (const float*)d_in[7];
    float* out = (float*)d_out;
    (void)d_ws; (void)ws_size;   // workspace no longer used

    // 32768 rows / 16 rows per block
    emis_kernel<<<2048, 256, 0, stream>>>(embed, W, bias, out);
    // one block per batch; chunk mats live entirely in LDS
    crf_fused<<<BB, 512, 0, stream>>>(out, tags, mask, start_t, end_t, trans, out);
}